// Round 6
// baseline (111.794 us; speedup 1.0000x reference)
//
#include <hip/hip_runtime.h>
#include <hip/hip_bf16.h>
#include <cstdint>
#include <cstddef>

#define NG 32
#define NP 64
#define ND 512
#define HW 192
#define EPSV 1e-5f

typedef _Float16 half8 __attribute__((ext_vector_type(8)));
typedef float floatx4 __attribute__((ext_vector_type(4)));
typedef float floatx16 __attribute__((ext_vector_type(16)));

// ---- probe pre-pass: prob[p][d][hw] f32 -> probT2[p][s][r][j] fp16 (s=d>>3, j=d&7)
// Fragment-ready k-major layout: a 32x32x16 A-frag load is one dwordx4 per lane.
__global__ __launch_bounds__(192) void prep_probe(const float* __restrict__ prob,
                                                  _Float16* __restrict__ probT2) {
  const int p = blockIdx.x, s = blockIdx.y;  // 64 x 64
  const int r = threadIdx.x;                 // 0..191
  const float* src = prob + ((size_t)p * ND + s * 8) * HW + r;
  half8 h;
#pragma unroll
  for (int j = 0; j < 8; ++j) h[j] = (_Float16)src[(size_t)j * HW];
  *(half8*)(probT2 + (((size_t)p * 64 + s) * HW + r) * 8) = h;
}

// ---- gal pre-pass: gal[g][d][x] f32 -> galT[g][x][d] fp16 (row-major, for LDS staging)
__global__ __launch_bounds__(256) void prep_gal(const float* __restrict__ gal,
                                                _Float16* __restrict__ galT) {
  __shared__ float tile[32][33];
  const int zg = blockIdx.z;
  const float* sp = gal + (size_t)zg * ND * HW;
  _Float16* dp = galT + (size_t)zg * HW * ND;
  const int k0 = blockIdx.x * 32, s0 = blockIdx.y * 32;
  const int tx = threadIdx.x & 31, ty = threadIdx.x >> 5;
#pragma unroll
  for (int i = ty; i < 32; i += 8)
    tile[i][tx] = sp[(size_t)(k0 + i) * HW + s0 + tx];
  __syncthreads();
#pragma unroll
  for (int i = ty; i < 32; i += 8)
    dp[(size_t)(s0 + i) * ND + k0 + tx] = (_Float16)tile[tx][i];
}

// ---- async 16B global -> LDS
__device__ __forceinline__ void g2l16(const void* g, void* l) {
  __builtin_amdgcn_global_load_lds(
      (const __attribute__((address_space(1))) void*)g,
      (__attribute__((address_space(3))) void*)l, 16, 0, 0);
}

// ---- main fused kernel: one WG (256 thr, 4 waves) per (g,p) pair ----
// 4 waves in 2(row wr) x 2(col wc) grid; each computes 96x96 via 3x3 frags of
// mfma_f32_32x32x16_f16.  B (gal) staged in LDS with CONFLICT-FREE layout
// [rowblock][slot][row32][16B] (BK=64, double-buffered); A (probe) loaded
// straight global->VGPR from fragment-ready probT2, register-double-buffered.
// Counted-vmcnt barrier keeps the A-prefetch in flight across the K-step sync.
__global__ __launch_bounds__(256, 2) void qaconv_main(
    const _Float16* __restrict__ galT, const _Float16* __restrict__ probT2,
    const float* __restrict__ bn_w, const float* __restrict__ bn_b,
    const float* __restrict__ bn_m, const float* __restrict__ bn_v,
    const float* __restrict__ fc_w, const float* __restrict__ fc_b,
    const float* __restrict__ lbn_w, const float* __restrict__ lbn_b,
    const float* __restrict__ lbn_m, const float* __restrict__ lbn_v,
    float* __restrict__ out) {
  // union: K-loop bufB[2][24576] (49152 B) ; epilogue rowbuf[192][66] f32 (50688 B)
  __shared__ __align__(16) char shmem[50688];
  __shared__ float colp[2][HW];
  __shared__ float wsum[4];
  char* bufB = shmem;
  float(*rowbuf)[66] = (float(*)[66])shmem;

  // probe-chunked XCD swizzle: XCD c gets probes [8c, 8c+8) x all g (probe data
  // 1.57 MB -> L2-resident per XCD; dominant A-traffic becomes L2 hits).
  const int i = blockIdx.x;
  const int L = (i & 7) * 256 + (i >> 3);  // 2048 % 8 == 0: bijective
  const int p = (L >> 8) * 8 + ((L & 255) >> 5);
  const int g = L & 31;

  const int t = threadIdx.x;
  const int lane = t & 63, wid = t >> 6;
  const int wr = wid & 1;   // probe-row half (y block of 96)
  const int wc = wid >> 1;  // gal-col half (x block of 96)
  const int l31 = lane & 31, hi = lane >> 5;
  const int arow0 = wr * 96 + l31;

  // A base: probT2 offset ((p*64 + s)*HW + r)*8, s = 2*idx + hi, idx = k-chunk 0..31
  const _Float16* aBase = probT2 + (((size_t)p * 64 + hi) * HW + arow0) * 8;

  // B staging source: thread t supplies (row = t&31, slot = (t>>5)&7), rowblock = round r.
  // LDS layout per buffer: off = rb*4096 + slot*512 + row*16  (conflict-free reads)
  const _Float16* gBl = galT + (size_t)g * HW * ND + (size_t)(t & 31) * ND + ((t >> 5) & 7) * 8;
  const int sdst = wid * 1024;  // wave-uniform LDS dest base (+ lane*16 by HW)

  floatx16 acc[3][3];
#pragma unroll
  for (int ii = 0; ii < 3; ++ii)
#pragma unroll
    for (int jj = 0; jj < 3; ++jj) acc[ii][jj] = (floatx16)0.f;

#define STAGE_B(kt_, buf_)                                          \
  {                                                                 \
    char* db_ = bufB + (buf_)*24576 + sdst;                         \
    const _Float16* sb_ = gBl + (size_t)(kt_)*64;                   \
    _Pragma("unroll") for (int r_ = 0; r_ < 6; ++r_)                \
        g2l16(sb_ + (size_t)r_ * 32 * ND, db_ + r_ * 4096);         \
  }

#define LOAD_AF(dst, idx_)                                          \
  {                                                                 \
    const _Float16* ap_ = aBase + (size_t)(idx_) * (2 * HW * 8);    \
    dst[0] = *(const half8*)(ap_);                                  \
    dst[1] = *(const half8*)(ap_ + 32 * 8);                         \
    dst[2] = *(const half8*)(ap_ + 64 * 8);                         \
  }

#define KC_BODY(kc_, AFU, AFL, nidx_)                                            \
  {                                                                              \
    LOAD_AF(AFL, nidx_);                                                         \
    half8 bf[3];                                                                 \
    const int boff_ = ((kc_)*2 + hi) * 512 + l31 * 16;                           \
    bf[0] = *(const half8*)(bcur + (wc * 3 + 0) * 4096 + boff_);                 \
    bf[1] = *(const half8*)(bcur + (wc * 3 + 1) * 4096 + boff_);                 \
    bf[2] = *(const half8*)(bcur + (wc * 3 + 2) * 4096 + boff_);                 \
    __builtin_amdgcn_s_setprio(1);                                               \
    _Pragma("unroll") for (int ii = 0; ii < 3; ++ii)                             \
        _Pragma("unroll") for (int jj = 0; jj < 3; ++jj)                         \
            acc[ii][jj] = __builtin_amdgcn_mfma_f32_32x32x16_f16(AFU[ii], bf[jj],\
                                                                 acc[ii][jj], 0, 0, 0); \
    __builtin_amdgcn_s_setprio(0);                                               \
  }

  half8 af0[3], af1[3];
  STAGE_B(0, 0);
  LOAD_AF(af0, 0);
  __syncthreads();  // prologue: full drain, B(0) staged by all waves

  for (int kt = 0; kt < 8; ++kt) {
    if (kt < 7) STAGE_B(kt + 1, (kt & 1) ^ 1);
    // pin stage issues ahead of KC bodies (ALU|VALU|SALU|MFMA|DS_READ may cross)
    __builtin_amdgcn_sched_barrier(0x10F);
    const char* bcur = bufB + (kt & 1) * 24576;
    const int i0 = kt * 4;
    const int n4 = (kt < 7) ? i0 + 4 : 31;  // clamp last prefetch (in-bounds dummy)
    KC_BODY(0, af0, af1, i0 + 1)
    KC_BODY(1, af1, af0, i0 + 2)
    KC_BODY(2, af0, af1, i0 + 3)
    KC_BODY(3, af1, af0, n4)
    // counted barrier: stages are already drained by af-consumption waits; only
    // KC3's 3 A-prefetch loads remain in flight -> let them cross the barrier.
    asm volatile("s_waitcnt vmcnt(3)" ::: "memory");
    __builtin_amdgcn_s_barrier();
  }

  // ---- epilogue: dual-axis max ----
  // C/D map: col X = wc*96 + fb*32 + l31, row Y = wr*96 + fa*32 + (e&3)+8*(e>>2)+4*hi
#pragma unroll
  for (int fb = 0; fb < 3; ++fb) {
    float v = -3.4e38f;
#pragma unroll
    for (int fa = 0; fa < 3; ++fa)
#pragma unroll
      for (int e = 0; e < 16; ++e) v = fmaxf(v, acc[fa][fb][e]);
    v = fmaxf(v, __shfl_xor(v, 32));
    if (lane < 32) colp[wr][wc * 96 + fb * 32 + lane] = v;
  }
  // rowmax partials -> rowbuf (overlays bufB; safe after the loop's final barrier)
#pragma unroll
  for (int fa = 0; fa < 3; ++fa)
#pragma unroll
    for (int e = 0; e < 16; ++e) {
      float rv = acc[fa][0][e];
      rv = fmaxf(rv, acc[fa][1][e]);
      rv = fmaxf(rv, acc[fa][2][e]);
      const int Y = wr * 96 + fa * 32 + (e & 3) + 8 * (e >> 2) + 4 * hi;
      rowbuf[Y][wc * 32 + l31] = rv;
    }
  __syncthreads();

  // ---- fused BN -> fc dot -> logit BN -> sigmoid ----
  float partial = 0.f;
  if (t < HW) {
    const float* rb = rowbuf[t];
    float rmax = -3.4e38f;
#pragma unroll
    for (int j = 0; j < 16; ++j) {
      const floatx4 v = *(const floatx4*)&rb[j * 4];
      rmax = fmaxf(rmax, fmaxf(fmaxf(v[0], v[1]), fmaxf(v[2], v[3])));
    }
    const float cmax = fmaxf(colp[0][t], colp[1][t]);
    const float scale = bn_w[0] / sqrtf(bn_v[0] + EPSV);
    const float bm = bn_m[0], bb = bn_b[0];
    partial = ((cmax - bm) * scale + bb) * fc_w[t] +
              ((rmax - bm) * scale + bb) * fc_w[HW + t];
  }
#pragma unroll
  for (int off = 1; off < 64; off <<= 1) partial += __shfl_xor(partial, off);
  if (lane == 0) wsum[wid] = partial;
  __syncthreads();
  if (t == 0) {
    const float sum = fc_b[0] + wsum[0] + wsum[1] + wsum[2] + wsum[3];
    const float logit = (sum - lbn_m[0]) * (lbn_w[0] / sqrtf(lbn_v[0] + EPSV)) + lbn_b[0];
    out[g * NP + p] = 1.f / (1.f + expf(-logit * 0.1f));
  }
#undef STAGE_B
#undef LOAD_AF
#undef KC_BODY
}

// ---------------- naive f32 fallback (only if ws too small) ----------------
__global__ __launch_bounds__(256) void qaconv_naive(
    const float* __restrict__ gal, const float* __restrict__ prob,
    const float* __restrict__ bn_w, const float* __restrict__ bn_b,
    const float* __restrict__ bn_m, const float* __restrict__ bn_v,
    const float* __restrict__ fc_w, const float* __restrict__ fc_b,
    const float* __restrict__ lbn_w, const float* __restrict__ lbn_b,
    const float* __restrict__ lbn_m, const float* __restrict__ lbn_v,
    float* __restrict__ out) {
  __shared__ float prow[ND];
  __shared__ float rowmaxs[HW];
  __shared__ float colmaxs[HW];
  __shared__ float red[4];
  const int bid = blockIdx.x;
  const int g = bid >> 6, p = bid & 63;
  const int t = threadIdx.x, lane = t & 63, wid = t >> 6;
  const float* gp = gal + (size_t)g * ND * HW;
  const float* pp = prob + (size_t)p * ND * HW;
  float colmax = -3.4e38f;
  for (int y = 0; y < HW; ++y) {
    for (int k = t; k < ND; k += 256) prow[k] = pp[(size_t)k * HW + y];
    __syncthreads();
    float sv = -3.4e38f;
    if (t < HW) {
      sv = 0.f;
      for (int k = 0; k < ND; ++k) sv = fmaf(prow[k], gp[(size_t)k * HW + t], sv);
      colmax = fmaxf(colmax, sv);
    }
    float m = sv;
#pragma unroll
    for (int off = 1; off < 64; off <<= 1) m = fmaxf(m, __shfl_xor(m, off));
    if (lane == 0) red[wid] = m;
    __syncthreads();
    if (t == 0) rowmaxs[y] = fmaxf(fmaxf(red[0], red[1]), fmaxf(red[2], red[3]));
    __syncthreads();
  }
  if (t < HW) colmaxs[t] = colmax;
  __syncthreads();
  float partial = 0.f;
  for (int j = t; j < 2 * HW; j += 256) {
    const float v = (j < HW) ? colmaxs[j] : rowmaxs[j - HW];
    const float sc = (v - bn_m[0]) * (bn_w[0] / sqrtf(bn_v[0] + EPSV)) + bn_b[0];
    partial += sc * fc_w[j];
  }
#pragma unroll
  for (int off = 1; off < 64; off <<= 1) partial += __shfl_xor(partial, off);
  if (lane == 0) red[wid] = partial;
  __syncthreads();
  if (t == 0) {
    const float sum = fc_b[0] + red[0] + red[1] + red[2] + red[3];
    const float logit = (sum - lbn_m[0]) * (lbn_w[0] / sqrtf(lbn_v[0] + EPSV)) + lbn_b[0];
    out[bid] = 1.f / (1.f + expf(-logit * 0.1f));
  }
}

extern "C" void kernel_launch(void* const* d_in, const int* in_sizes, int n_in,
                              void* d_out, int out_size, void* d_ws, size_t ws_size,
                              hipStream_t stream) {
  const float* gal = (const float*)d_in[0];
  const float* prob = (const float*)d_in[1];
  const float* bn_w = (const float*)d_in[2];
  const float* bn_b = (const float*)d_in[3];
  const float* bn_m = (const float*)d_in[4];
  const float* bn_v = (const float*)d_in[5];
  const float* fc_w = (const float*)d_in[6];
  const float* fc_b = (const float*)d_in[7];
  const float* lbn_w = (const float*)d_in[8];
  const float* lbn_b = (const float*)d_in[9];
  const float* lbn_m = (const float*)d_in[10];
  const float* lbn_v = (const float*)d_in[11];
  float* out = (float*)d_out;

  const size_t probT2_elems = (size_t)NP * 64 * HW * 8;  // 6.29M halves
  const size_t galT_elems = (size_t)NG * HW * ND;        // 3.15M halves
  const size_t ws_needed = (probT2_elems + galT_elems) * sizeof(_Float16);
  if (ws_size >= ws_needed) {
    _Float16* probT2 = (_Float16*)d_ws;
    _Float16* galT = probT2 + probT2_elems;
    prep_probe<<<dim3(NP, 64), dim3(192), 0, stream>>>(prob, probT2);
    prep_gal<<<dim3(16, 6, NG), dim3(256), 0, stream>>>(gal, galT);
    qaconv_main<<<dim3(NG * NP), dim3(256), 0, stream>>>(
        galT, probT2, bn_w, bn_b, bn_m, bn_v, fc_w, fc_b, lbn_w, lbn_b, lbn_m, lbn_v, out);
  } else {
    qaconv_naive<<<dim3(NG * NP), dim3(256), 0, stream>>>(
        gal, prob, bn_w, bn_b, bn_m, bn_v, fc_w, fc_b, lbn_w, lbn_b, lbn_m, lbn_v, out);
  }
}

// Round 7
// 108.588 us; speedup vs baseline: 1.0295x; 1.0295x over previous
//
#include <hip/hip_runtime.h>
#include <hip/hip_bf16.h>
#include <cstdint>
#include <cstddef>

#define NG 32
#define NP 64
#define ND 512
#define HW 192
#define EPSV 1e-5f

typedef _Float16 half8 __attribute__((ext_vector_type(8)));
typedef float floatx4 __attribute__((ext_vector_type(4)));
typedef float floatx16 __attribute__((ext_vector_type(16)));

// ---- probe pre-pass: prob[p][d][hw] f32 -> probT2[p][s][r][j] fp16 (s=d>>3, j=d&7)
// Fragment-ready k-major layout: a 32x32x16 A-frag load is one dwordx4 per lane.
__global__ __launch_bounds__(192) void prep_probe(const float* __restrict__ prob,
                                                  _Float16* __restrict__ probT2) {
  const int p = blockIdx.x, s = blockIdx.y;  // 64 x 64
  const int r = threadIdx.x;                 // 0..191
  const float* src = prob + ((size_t)p * ND + s * 8) * HW + r;
  half8 h;
#pragma unroll
  for (int j = 0; j < 8; ++j) h[j] = (_Float16)src[(size_t)j * HW];
  *(half8*)(probT2 + (((size_t)p * 64 + s) * HW + r) * 8) = h;
}

// ---- gal pre-pass: gal[g][d][x] f32 -> galT[g][x][d] fp16 (row-major, for LDS staging)
__global__ __launch_bounds__(256) void prep_gal(const float* __restrict__ gal,
                                                _Float16* __restrict__ galT) {
  __shared__ float tile[32][33];
  const int zg = blockIdx.z;
  const float* sp = gal + (size_t)zg * ND * HW;
  _Float16* dp = galT + (size_t)zg * HW * ND;
  const int k0 = blockIdx.x * 32, s0 = blockIdx.y * 32;
  const int tx = threadIdx.x & 31, ty = threadIdx.x >> 5;
#pragma unroll
  for (int i = ty; i < 32; i += 8)
    tile[i][tx] = sp[(size_t)(k0 + i) * HW + s0 + tx];
  __syncthreads();
#pragma unroll
  for (int i = ty; i < 32; i += 8)
    dp[(size_t)(s0 + i) * ND + k0 + tx] = (_Float16)tile[tx][i];
}

// ---- async 16B global -> LDS
__device__ __forceinline__ void g2l16(const void* g, void* l) {
  __builtin_amdgcn_global_load_lds(
      (const __attribute__((address_space(1))) void*)g,
      (__attribute__((address_space(3))) void*)l, 16, 0, 0);
}

// ---- main fused kernel: one WG (256 thr, 4 waves) per (g,p) pair ----
// 4 waves in 2(row wr) x 2(col wc) grid; each computes 96x96 via 3x3 frags of
// mfma_f32_32x32x16_f16.  B (gal) staged in LDS with CONFLICT-FREE layout
// [rowblock][slot][row32][16B] (BK=64, double-buffered); A (probe) loaded
// straight global->VGPR from fragment-ready probT2, register-double-buffered.
// Counted-vmcnt barrier keeps the A-prefetch in flight across the K-step sync.
// Block order: plain bid = g*64+p (R6's XCD swizzle caused 5x HBM over-fetch).
__global__ __launch_bounds__(256, 2) void qaconv_main(
    const _Float16* __restrict__ galT, const _Float16* __restrict__ probT2,
    const float* __restrict__ bn_w, const float* __restrict__ bn_b,
    const float* __restrict__ bn_m, const float* __restrict__ bn_v,
    const float* __restrict__ fc_w, const float* __restrict__ fc_b,
    const float* __restrict__ lbn_w, const float* __restrict__ lbn_b,
    const float* __restrict__ lbn_m, const float* __restrict__ lbn_v,
    float* __restrict__ out) {
  // union: K-loop bufB[2][24576] (49152 B) ; epilogue rowbuf[192][66] f32 (50688 B)
  __shared__ __align__(16) char shmem[50688];
  __shared__ float colp[2][HW];
  __shared__ float wsum[4];
  char* bufB = shmem;
  float(*rowbuf)[66] = (float(*)[66])shmem;

  const int bid = blockIdx.x;
  const int g = bid >> 6, p = bid & 63;

  const int t = threadIdx.x;
  const int lane = t & 63, wid = t >> 6;
  const int wr = wid & 1;   // probe-row half (y block of 96)
  const int wc = wid >> 1;  // gal-col half (x block of 96)
  const int l31 = lane & 31, hi = lane >> 5;
  const int arow0 = wr * 96 + l31;

  // A base: probT2 offset ((p*64 + s)*HW + r)*8, s = 2*idx + hi, idx = k-chunk 0..31
  const _Float16* aBase = probT2 + (((size_t)p * 64 + hi) * HW + arow0) * 8;

  // B staging source: thread t supplies (row = t&31, slot = (t>>5)&7), rowblock = round r.
  // LDS layout per buffer: off = rb*4096 + slot*512 + row*16  (conflict-free reads)
  const _Float16* gBl = galT + (size_t)g * HW * ND + (size_t)(t & 31) * ND + ((t >> 5) & 7) * 8;
  const int sdst = wid * 1024;  // wave-uniform LDS dest base (+ lane*16 by HW)

  floatx16 acc[3][3];
#pragma unroll
  for (int ii = 0; ii < 3; ++ii)
#pragma unroll
    for (int jj = 0; jj < 3; ++jj) acc[ii][jj] = (floatx16)0.f;

#define STAGE_B(kt_, buf_)                                          \
  {                                                                 \
    char* db_ = bufB + (buf_)*24576 + sdst;                         \
    const _Float16* sb_ = gBl + (size_t)(kt_)*64;                   \
    _Pragma("unroll") for (int r_ = 0; r_ < 6; ++r_)                \
        g2l16(sb_ + (size_t)r_ * 32 * ND, db_ + r_ * 4096);         \
  }

#define LOAD_AF(dst, idx_)                                          \
  {                                                                 \
    const _Float16* ap_ = aBase + (size_t)(idx_) * (2 * HW * 8);    \
    dst[0] = *(const half8*)(ap_);                                  \
    dst[1] = *(const half8*)(ap_ + 32 * 8);                         \
    dst[2] = *(const half8*)(ap_ + 64 * 8);                         \
  }

#define KC_BODY(kc_, AFU, AFL, nidx_)                                            \
  {                                                                              \
    LOAD_AF(AFL, nidx_);                                                         \
    half8 bf[3];                                                                 \
    const int boff_ = ((kc_)*2 + hi) * 512 + l31 * 16;                           \
    bf[0] = *(const half8*)(bcur + (wc * 3 + 0) * 4096 + boff_);                 \
    bf[1] = *(const half8*)(bcur + (wc * 3 + 1) * 4096 + boff_);                 \
    bf[2] = *(const half8*)(bcur + (wc * 3 + 2) * 4096 + boff_);                 \
    __builtin_amdgcn_s_setprio(1);                                               \
    _Pragma("unroll") for (int ii = 0; ii < 3; ++ii)                             \
        _Pragma("unroll") for (int jj = 0; jj < 3; ++jj)                         \
            acc[ii][jj] = __builtin_amdgcn_mfma_f32_32x32x16_f16(AFU[ii], bf[jj],\
                                                                 acc[ii][jj], 0, 0, 0); \
    __builtin_amdgcn_s_setprio(0);                                               \
  }

  half8 af0[3], af1[3];
  STAGE_B(0, 0);
  LOAD_AF(af0, 0);
  __syncthreads();  // prologue: full drain, B(0) staged by all waves

  for (int kt = 0; kt < 8; ++kt) {
    if (kt < 7) STAGE_B(kt + 1, (kt & 1) ^ 1);
    // pin stage issues ahead of KC bodies (ALU|VALU|SALU|MFMA|DS_READ may cross)
    __builtin_amdgcn_sched_barrier(0x10F);
    const char* bcur = bufB + (kt & 1) * 24576;
    const int i0 = kt * 4;
    const int n4 = (kt < 7) ? i0 + 4 : 31;  // clamp last prefetch (in-bounds dummy)
    KC_BODY(0, af0, af1, i0 + 1)
    KC_BODY(1, af1, af0, i0 + 2)
    KC_BODY(2, af0, af1, i0 + 3)
    KC_BODY(3, af1, af0, n4)
    // counted barrier: stages are already drained by af-consumption waits; only
    // KC3's 3 A-prefetch loads remain in flight -> let them cross the barrier.
    asm volatile("s_waitcnt vmcnt(3)" ::: "memory");
    __builtin_amdgcn_s_barrier();
  }

  // ---- epilogue: dual-axis max ----
  // C/D map: col X = wc*96 + fb*32 + l31, row Y = wr*96 + fa*32 + (e&3)+8*(e>>2)+4*hi
#pragma unroll
  for (int fb = 0; fb < 3; ++fb) {
    float v = -3.4e38f;
#pragma unroll
    for (int fa = 0; fa < 3; ++fa)
#pragma unroll
      for (int e = 0; e < 16; ++e) v = fmaxf(v, acc[fa][fb][e]);
    v = fmaxf(v, __shfl_xor(v, 32));
    if (lane < 32) colp[wr][wc * 96 + fb * 32 + lane] = v;
  }
  // rowmax partials -> rowbuf (overlays bufB; safe after the loop's final barrier)
#pragma unroll
  for (int fa = 0; fa < 3; ++fa)
#pragma unroll
    for (int e = 0; e < 16; ++e) {
      float rv = acc[fa][0][e];
      rv = fmaxf(rv, acc[fa][1][e]);
      rv = fmaxf(rv, acc[fa][2][e]);
      const int Y = wr * 96 + fa * 32 + (e & 3) + 8 * (e >> 2) + 4 * hi;
      rowbuf[Y][wc * 32 + l31] = rv;
    }
  __syncthreads();

  // ---- fused BN -> fc dot -> logit BN -> sigmoid ----
  float partial = 0.f;
  if (t < HW) {
    const float* rb = rowbuf[t];
    float rmax = -3.4e38f;
#pragma unroll
    for (int j = 0; j < 16; ++j) {
      const floatx4 v = *(const floatx4*)&rb[j * 4];
      rmax = fmaxf(rmax, fmaxf(fmaxf(v[0], v[1]), fmaxf(v[2], v[3])));
    }
    const float cmax = fmaxf(colp[0][t], colp[1][t]);
    const float scale = bn_w[0] / sqrtf(bn_v[0] + EPSV);
    const float bm = bn_m[0], bb = bn_b[0];
    partial = ((cmax - bm) * scale + bb) * fc_w[t] +
              ((rmax - bm) * scale + bb) * fc_w[HW + t];
  }
#pragma unroll
  for (int off = 1; off < 64; off <<= 1) partial += __shfl_xor(partial, off);
  if (lane == 0) wsum[wid] = partial;
  __syncthreads();
  if (t == 0) {
    const float sum = fc_b[0] + wsum[0] + wsum[1] + wsum[2] + wsum[3];
    const float logit = (sum - lbn_m[0]) * (lbn_w[0] / sqrtf(lbn_v[0] + EPSV)) + lbn_b[0];
    out[bid] = 1.f / (1.f + expf(-logit * 0.1f));
  }
#undef STAGE_B
#undef LOAD_AF
#undef KC_BODY
}

// ---------------- naive f32 fallback (only if ws too small) ----------------
__global__ __launch_bounds__(256) void qaconv_naive(
    const float* __restrict__ gal, const float* __restrict__ prob,
    const float* __restrict__ bn_w, const float* __restrict__ bn_b,
    const float* __restrict__ bn_m, const float* __restrict__ bn_v,
    const float* __restrict__ fc_w, const float* __restrict__ fc_b,
    const float* __restrict__ lbn_w, const float* __restrict__ lbn_b,
    const float* __restrict__ lbn_m, const float* __restrict__ lbn_v,
    float* __restrict__ out) {
  __shared__ float prow[ND];
  __shared__ float rowmaxs[HW];
  __shared__ float colmaxs[HW];
  __shared__ float red[4];
  const int bid = blockIdx.x;
  const int g = bid >> 6, p = bid & 63;
  const int t = threadIdx.x, lane = t & 63, wid = t >> 6;
  const float* gp = gal + (size_t)g * ND * HW;
  const float* pp = prob + (size_t)p * ND * HW;
  float colmax = -3.4e38f;
  for (int y = 0; y < HW; ++y) {
    for (int k = t; k < ND; k += 256) prow[k] = pp[(size_t)k * HW + y];
    __syncthreads();
    float sv = -3.4e38f;
    if (t < HW) {
      sv = 0.f;
      for (int k = 0; k < ND; ++k) sv = fmaf(prow[k], gp[(size_t)k * HW + t], sv);
      colmax = fmaxf(colmax, sv);
    }
    float m = sv;
#pragma unroll
    for (int off = 1; off < 64; off <<= 1) m = fmaxf(m, __shfl_xor(m, off));
    if (lane == 0) red[wid] = m;
    __syncthreads();
    if (t == 0) rowmaxs[y] = fmaxf(fmaxf(red[0], red[1]), fmaxf(red[2], red[3]));
    __syncthreads();
  }
  if (t < HW) colmaxs[t] = colmax;
  __syncthreads();
  float partial = 0.f;
  for (int j = t; j < 2 * HW; j += 256) {
    const float v = (j < HW) ? colmaxs[j] : rowmaxs[j - HW];
    const float sc = (v - bn_m[0]) * (bn_w[0] / sqrtf(bn_v[0] + EPSV)) + bn_b[0];
    partial += sc * fc_w[j];
  }
#pragma unroll
  for (int off = 1; off < 64; off <<= 1) partial += __shfl_xor(partial, off);
  if (lane == 0) red[wid] = partial;
  __syncthreads();
  if (t == 0) {
    const float sum = fc_b[0] + red[0] + red[1] + red[2] + red[3];
    const float logit = (sum - lbn_m[0]) * (lbn_w[0] / sqrtf(lbn_v[0] + EPSV)) + lbn_b[0];
    out[bid] = 1.f / (1.f + expf(-logit * 0.1f));
  }
}

extern "C" void kernel_launch(void* const* d_in, const int* in_sizes, int n_in,
                              void* d_out, int out_size, void* d_ws, size_t ws_size,
                              hipStream_t stream) {
  const float* gal = (const float*)d_in[0];
  const float* prob = (const float*)d_in[1];
  const float* bn_w = (const float*)d_in[2];
  const float* bn_b = (const float*)d_in[3];
  const float* bn_m = (const float*)d_in[4];
  const float* bn_v = (const float*)d_in[5];
  const float* fc_w = (const float*)d_in[6];
  const float* fc_b = (const float*)d_in[7];
  const float* lbn_w = (const float*)d_in[8];
  const float* lbn_b = (const float*)d_in[9];
  const float* lbn_m = (const float*)d_in[10];
  const float* lbn_v = (const float*)d_in[11];
  float* out = (float*)d_out;

  const size_t probT2_elems = (size_t)NP * 64 * HW * 8;  // 6.29M halves
  const size_t galT_elems = (size_t)NG * HW * ND;        // 3.15M halves
  const size_t ws_needed = (probT2_elems + galT_elems) * sizeof(_Float16);
  if (ws_size >= ws_needed) {
    _Float16* probT2 = (_Float16*)d_ws;
    _Float16* galT = probT2 + probT2_elems;
    prep_probe<<<dim3(NP, 64), dim3(192), 0, stream>>>(prob, probT2);
    prep_gal<<<dim3(16, 6, NG), dim3(256), 0, stream>>>(gal, galT);
    qaconv_main<<<dim3(NG * NP), dim3(256), 0, stream>>>(
        galT, probT2, bn_w, bn_b, bn_m, bn_v, fc_w, fc_b, lbn_w, lbn_b, lbn_m, lbn_v, out);
  } else {
    qaconv_naive<<<dim3(NG * NP), dim3(256), 0, stream>>>(
        gal, prob, bn_w, bn_b, bn_m, bn_v, fc_w, fc_b, lbn_w, lbn_b, lbn_m, lbn_v, out);
  }
}

// Round 8
// 108.540 us; speedup vs baseline: 1.0300x; 1.0004x over previous
//
#include <hip/hip_runtime.h>
#include <hip/hip_bf16.h>
#include <cstdint>
#include <cstddef>

#define NG 32
#define NP 64
#define ND 512
#define HW 192
#define EPSV 1e-5f

typedef _Float16 half8 __attribute__((ext_vector_type(8)));
typedef float floatx4 __attribute__((ext_vector_type(4)));
typedef float floatx16 __attribute__((ext_vector_type(16)));

// ---- probe pre-pass: prob[p][d][hw] f32 -> probT2[p][s][r][j] fp16 (s=d>>3, j=d&7)
// Fragment-ready k-major layout: a 32x32x16 A-frag load is one dwordx4 per lane.
__global__ __launch_bounds__(192) void prep_probe(const float* __restrict__ prob,
                                                  _Float16* __restrict__ probT2) {
  const int p = blockIdx.x, s = blockIdx.y;  // 64 x 64
  const int r = threadIdx.x;                 // 0..191
  const float* src = prob + ((size_t)p * ND + s * 8) * HW + r;
  half8 h;
#pragma unroll
  for (int j = 0; j < 8; ++j) h[j] = (_Float16)src[(size_t)j * HW];
  *(half8*)(probT2 + (((size_t)p * 64 + s) * HW + r) * 8) = h;
}

// ---- gal pre-pass: gal[g][d][x] f32 -> galT[g][x][d] fp16 (row-major, for LDS staging)
__global__ __launch_bounds__(256) void prep_gal(const float* __restrict__ gal,
                                                _Float16* __restrict__ galT) {
  __shared__ float tile[32][33];
  const int zg = blockIdx.z;
  const float* sp = gal + (size_t)zg * ND * HW;
  _Float16* dp = galT + (size_t)zg * HW * ND;
  const int k0 = blockIdx.x * 32, s0 = blockIdx.y * 32;
  const int tx = threadIdx.x & 31, ty = threadIdx.x >> 5;
#pragma unroll
  for (int i = ty; i < 32; i += 8)
    tile[i][tx] = sp[(size_t)(k0 + i) * HW + s0 + tx];
  __syncthreads();
#pragma unroll
  for (int i = ty; i < 32; i += 8)
    dp[(size_t)(s0 + i) * ND + k0 + tx] = (_Float16)tile[tx][i];
}

// ---- async 16B global -> LDS
__device__ __forceinline__ void g2l16(const void* g, void* l) {
  __builtin_amdgcn_global_load_lds(
      (const __attribute__((address_space(1))) void*)g,
      (__attribute__((address_space(3))) void*)l, 16, 0, 0);
}

// ---- main fused kernel: one WG (256 thr, 4 waves) per (g,p) pair ----
// 4 waves in 2(row wr) x 2(col wc) grid; each computes 96x96 via 3x3 frags of
// mfma_f32_32x32x16_f16.  B (gal) staged in LDS with CONFLICT-FREE layout
// [rowblock][slot][row32][16B] (BK=64, double-buffered); A (probe) loaded
// straight global->VGPR from fragment-ready probT2, register-double-buffered.
// Scheduling = R5's proven structure: one plain __syncthreads per K-step, no
// sched_barrier / counted-vmcnt (R7 showed those serialize A-loads behind the
// B-stage queue: vmcnt is in-order, so af-waits forced full stage drains).
__global__ __launch_bounds__(256, 2) void qaconv_main(
    const _Float16* __restrict__ galT, const _Float16* __restrict__ probT2,
    const float* __restrict__ bn_w, const float* __restrict__ bn_b,
    const float* __restrict__ bn_m, const float* __restrict__ bn_v,
    const float* __restrict__ fc_w, const float* __restrict__ fc_b,
    const float* __restrict__ lbn_w, const float* __restrict__ lbn_b,
    const float* __restrict__ lbn_m, const float* __restrict__ lbn_v,
    float* __restrict__ out) {
  // union: K-loop bufB[2][24576] (49152 B) ; epilogue rowbuf[192][66] f32 (50688 B)
  __shared__ __align__(16) char shmem[50688];
  __shared__ float colp[2][HW];
  __shared__ float wsum[4];
  char* bufB = shmem;
  float(*rowbuf)[66] = (float(*)[66])shmem;

  const int bid = blockIdx.x;
  const int g = bid >> 6, p = bid & 63;

  const int t = threadIdx.x;
  const int lane = t & 63, wid = t >> 6;
  const int wr = wid & 1;   // probe-row half (y block of 96)
  const int wc = wid >> 1;  // gal-col half (x block of 96)
  const int l31 = lane & 31, hi = lane >> 5;
  const int arow0 = wr * 96 + l31;

  // A base: probT2 offset ((p*64 + s)*HW + r)*8, s = 2*idx + hi, idx = k-chunk 0..31
  const _Float16* aBase = probT2 + (((size_t)p * 64 + hi) * HW + arow0) * 8;

  // B staging source: thread t supplies (row = t&31, slot = (t>>5)&7), rowblock = round r.
  // LDS layout per buffer: off = rb*4096 + slot*512 + row*16  (conflict-free reads:
  // each half-wave reads 512 contiguous bytes)
  const _Float16* gBl = galT + (size_t)g * HW * ND + (size_t)(t & 31) * ND + ((t >> 5) & 7) * 8;
  const int sdst = wid * 1024;  // wave-uniform LDS dest base (+ lane*16 by HW)

  floatx16 acc[3][3];
#pragma unroll
  for (int ii = 0; ii < 3; ++ii)
#pragma unroll
    for (int jj = 0; jj < 3; ++jj) acc[ii][jj] = (floatx16)0.f;

#define STAGE_B(kt_, buf_)                                          \
  {                                                                 \
    char* db_ = bufB + (buf_)*24576 + sdst;                         \
    const _Float16* sb_ = gBl + (size_t)(kt_)*64;                   \
    _Pragma("unroll") for (int r_ = 0; r_ < 6; ++r_)                \
        g2l16(sb_ + (size_t)r_ * 32 * ND, db_ + r_ * 4096);         \
  }

#define LOAD_AF(dst, idx_)                                          \
  {                                                                 \
    const _Float16* ap_ = aBase + (size_t)(idx_) * (2 * HW * 8);    \
    dst[0] = *(const half8*)(ap_);                                  \
    dst[1] = *(const half8*)(ap_ + 32 * 8);                         \
    dst[2] = *(const half8*)(ap_ + 64 * 8);                         \
  }

#define KC_BODY(kc_, AFU, AFL, nidx_)                                            \
  {                                                                              \
    LOAD_AF(AFL, nidx_);                                                         \
    half8 bf[3];                                                                 \
    const int boff_ = ((kc_)*2 + hi) * 512 + l31 * 16;                           \
    bf[0] = *(const half8*)(bcur + (wc * 3 + 0) * 4096 + boff_);                 \
    bf[1] = *(const half8*)(bcur + (wc * 3 + 1) * 4096 + boff_);                 \
    bf[2] = *(const half8*)(bcur + (wc * 3 + 2) * 4096 + boff_);                 \
    __builtin_amdgcn_s_setprio(1);                                               \
    _Pragma("unroll") for (int ii = 0; ii < 3; ++ii)                             \
        _Pragma("unroll") for (int jj = 0; jj < 3; ++jj)                         \
            acc[ii][jj] = __builtin_amdgcn_mfma_f32_32x32x16_f16(AFU[ii], bf[jj],\
                                                                 acc[ii][jj], 0, 0, 0); \
    __builtin_amdgcn_s_setprio(0);                                               \
  }

  half8 af0[3], af1[3];
  STAGE_B(0, 0);
  LOAD_AF(af0, 0);
  __syncthreads();  // prologue: full drain, B(0) staged by all waves

  for (int kt = 0; kt < 8; ++kt) {
    if (kt < 7) STAGE_B(kt + 1, (kt & 1) ^ 1);
    const char* bcur = bufB + (kt & 1) * 24576;
    const int i0 = kt * 4;
    const int n4 = (kt < 7) ? i0 + 4 : 31;  // clamp last prefetch (in-bounds dummy)
    KC_BODY(0, af0, af1, i0 + 1)
    KC_BODY(1, af1, af0, i0 + 2)
    KC_BODY(2, af0, af1, i0 + 3)
    KC_BODY(3, af1, af0, n4)
    __syncthreads();  // stage(kt+1) drained; all waves done reading bufB[kt&1]
  }

  // ---- epilogue: dual-axis max ----
  // C/D map: col X = wc*96 + fb*32 + l31, row Y = wr*96 + fa*32 + (e&3)+8*(e>>2)+4*hi
#pragma unroll
  for (int fb = 0; fb < 3; ++fb) {
    float v = -3.4e38f;
#pragma unroll
    for (int fa = 0; fa < 3; ++fa)
#pragma unroll
      for (int e = 0; e < 16; ++e) v = fmaxf(v, acc[fa][fb][e]);
    v = fmaxf(v, __shfl_xor(v, 32));
    if (lane < 32) colp[wr][wc * 96 + fb * 32 + lane] = v;
  }
  // rowmax partials -> rowbuf (overlays bufB; safe after the loop's final barrier)
#pragma unroll
  for (int fa = 0; fa < 3; ++fa)
#pragma unroll
    for (int e = 0; e < 16; ++e) {
      float rv = acc[fa][0][e];
      rv = fmaxf(rv, acc[fa][1][e]);
      rv = fmaxf(rv, acc[fa][2][e]);
      const int Y = wr * 96 + fa * 32 + (e & 3) + 8 * (e >> 2) + 4 * hi;
      rowbuf[Y][wc * 32 + l31] = rv;
    }
  __syncthreads();

  // ---- fused BN -> fc dot -> logit BN -> sigmoid ----
  float partial = 0.f;
  if (t < HW) {
    const float* rb = rowbuf[t];
    float rmax = -3.4e38f;
#pragma unroll
    for (int j = 0; j < 16; ++j) {
      const floatx4 v = *(const floatx4*)&rb[j * 4];
      rmax = fmaxf(rmax, fmaxf(fmaxf(v[0], v[1]), fmaxf(v[2], v[3])));
    }
    const float cmax = fmaxf(colp[0][t], colp[1][t]);
    const float scale = bn_w[0] / sqrtf(bn_v[0] + EPSV);
    const float bm = bn_m[0], bb = bn_b[0];
    partial = ((cmax - bm) * scale + bb) * fc_w[t] +
              ((rmax - bm) * scale + bb) * fc_w[HW + t];
  }
#pragma unroll
  for (int off = 1; off < 64; off <<= 1) partial += __shfl_xor(partial, off);
  if (lane == 0) wsum[wid] = partial;
  __syncthreads();
  if (t == 0) {
    const float sum = fc_b[0] + wsum[0] + wsum[1] + wsum[2] + wsum[3];
    const float logit = (sum - lbn_m[0]) * (lbn_w[0] / sqrtf(lbn_v[0] + EPSV)) + lbn_b[0];
    out[bid] = 1.f / (1.f + expf(-logit * 0.1f));
  }
#undef STAGE_B
#undef LOAD_AF
#undef KC_BODY
}

// ---------------- naive f32 fallback (only if ws too small) ----------------
__global__ __launch_bounds__(256) void qaconv_naive(
    const float* __restrict__ gal, const float* __restrict__ prob,
    const float* __restrict__ bn_w, const float* __restrict__ bn_b,
    const float* __restrict__ bn_m, const float* __restrict__ bn_v,
    const float* __restrict__ fc_w, const float* __restrict__ fc_b,
    const float* __restrict__ lbn_w, const float* __restrict__ lbn_b,
    const float* __restrict__ lbn_m, const float* __restrict__ lbn_v,
    float* __restrict__ out) {
  __shared__ float prow[ND];
  __shared__ float rowmaxs[HW];
  __shared__ float colmaxs[HW];
  __shared__ float red[4];
  const int bid = blockIdx.x;
  const int g = bid >> 6, p = bid & 63;
  const int t = threadIdx.x, lane = t & 63, wid = t >> 6;
  const float* gp = gal + (size_t)g * ND * HW;
  const float* pp = prob + (size_t)p * ND * HW;
  float colmax = -3.4e38f;
  for (int y = 0; y < HW; ++y) {
    for (int k = t; k < ND; k += 256) prow[k] = pp[(size_t)k * HW + y];
    __syncthreads();
    float sv = -3.4e38f;
    if (t < HW) {
      sv = 0.f;
      for (int k = 0; k < ND; ++k) sv = fmaf(prow[k], gp[(size_t)k * HW + t], sv);
      colmax = fmaxf(colmax, sv);
    }
    float m = sv;
#pragma unroll
    for (int off = 1; off < 64; off <<= 1) m = fmaxf(m, __shfl_xor(m, off));
    if (lane == 0) red[wid] = m;
    __syncthreads();
    if (t == 0) rowmaxs[y] = fmaxf(fmaxf(red[0], red[1]), fmaxf(red[2], red[3]));
    __syncthreads();
  }
  if (t < HW) colmaxs[t] = colmax;
  __syncthreads();
  float partial = 0.f;
  for (int j = t; j < 2 * HW; j += 256) {
    const float v = (j < HW) ? colmaxs[j] : rowmaxs[j - HW];
    const float sc = (v - bn_m[0]) * (bn_w[0] / sqrtf(bn_v[0] + EPSV)) + bn_b[0];
    partial += sc * fc_w[j];
  }
#pragma unroll
  for (int off = 1; off < 64; off <<= 1) partial += __shfl_xor(partial, off);
  if (lane == 0) red[wid] = partial;
  __syncthreads();
  if (t == 0) {
    const float sum = fc_b[0] + red[0] + red[1] + red[2] + red[3];
    const float logit = (sum - lbn_m[0]) * (lbn_w[0] / sqrtf(lbn_v[0] + EPSV)) + lbn_b[0];
    out[bid] = 1.f / (1.f + expf(-logit * 0.1f));
  }
}

extern "C" void kernel_launch(void* const* d_in, const int* in_sizes, int n_in,
                              void* d_out, int out_size, void* d_ws, size_t ws_size,
                              hipStream_t stream) {
  const float* gal = (const float*)d_in[0];
  const float* prob = (const float*)d_in[1];
  const float* bn_w = (const float*)d_in[2];
  const float* bn_b = (const float*)d_in[3];
  const float* bn_m = (const float*)d_in[4];
  const float* bn_v = (const float*)d_in[5];
  const float* fc_w = (const float*)d_in[6];
  const float* fc_b = (const float*)d_in[7];
  const float* lbn_w = (const float*)d_in[8];
  const float* lbn_b = (const float*)d_in[9];
  const float* lbn_m = (const float*)d_in[10];
  const float* lbn_v = (const float*)d_in[11];
  float* out = (float*)d_out;

  const size_t probT2_elems = (size_t)NP * 64 * HW * 8;  // 6.29M halves
  const size_t galT_elems = (size_t)NG * HW * ND;        // 3.15M halves
  const size_t ws_needed = (probT2_elems + galT_elems) * sizeof(_Float16);
  if (ws_size >= ws_needed) {
    _Float16* probT2 = (_Float16*)d_ws;
    _Float16* galT = probT2 + probT2_elems;
    prep_probe<<<dim3(NP, 64), dim3(192), 0, stream>>>(prob, probT2);
    prep_gal<<<dim3(16, 6, NG), dim3(256), 0, stream>>>(gal, galT);
    qaconv_main<<<dim3(NG * NP), dim3(256), 0, stream>>>(
        galT, probT2, bn_w, bn_b, bn_m, bn_v, fc_w, fc_b, lbn_w, lbn_b, lbn_m, lbn_v, out);
  } else {
    qaconv_naive<<<dim3(NG * NP), dim3(256), 0, stream>>>(
        gal, prob, bn_w, bn_b, bn_m, bn_v, fc_w, fc_b, lbn_w, lbn_b, lbn_m, lbn_v, out);
  }
}

// Round 9
// 92.458 us; speedup vs baseline: 1.2091x; 1.1739x over previous
//
#include <hip/hip_runtime.h>
#include <hip/hip_bf16.h>
#include <cstdint>
#include <cstddef>

#define NG 32
#define NP 64
#define ND 512
#define HW 192
#define EPSV 1e-5f

typedef _Float16 half8 __attribute__((ext_vector_type(8)));
typedef float floatx4 __attribute__((ext_vector_type(4)));
typedef float floatx16 __attribute__((ext_vector_type(16)));

// ---- probe pre-pass: prob[p][d][hw] f32 -> probT2[p][s][r][j] fp16 (s=d>>3, j=d&7)
// Fragment-ready k-major layout: a 32x32x16 A-frag load is one dwordx4 per lane.
__global__ __launch_bounds__(192) void prep_probe(const float* __restrict__ prob,
                                                  _Float16* __restrict__ probT2) {
  const int p = blockIdx.x, s = blockIdx.y;  // 64 x 64
  const int r = threadIdx.x;                 // 0..191
  const float* src = prob + ((size_t)p * ND + s * 8) * HW + r;
  half8 h;
#pragma unroll
  for (int j = 0; j < 8; ++j) h[j] = (_Float16)src[(size_t)j * HW];
  *(half8*)(probT2 + (((size_t)p * 64 + s) * HW + r) * 8) = h;
}

// ---- gal pre-pass: gal[g][d][x] f32 -> galT2[g][kt][rb][slot][row][j] fp16,
// d = kt*64 + slot*8 + j, x = rb*32 + row.  This is BYTE-IDENTICAL to the LDS
// tile layout, so staging is a linear contiguous copy (1KB per wave-instr) and
// LDS reads stay conflict-free.
__global__ __launch_bounds__(256) void prep_gal2(const float* __restrict__ gal,
                                                 _Float16* __restrict__ galT2) {
  __shared__ _Float16 lds[64 * 192];  // [d][x]
  const int g = blockIdx.x, kt = blockIdx.y;
  const int t = threadIdx.x;
  const int lane = t & 63, wid = t >> 6;
  const float* src = gal + ((size_t)g * ND + kt * 64) * HW;
#pragma unroll
  for (int dd = 0; dd < 16; ++dd) {
    const int d = dd * 4 + wid;
#pragma unroll
    for (int c = 0; c < 3; ++c) {
      const int x = c * 64 + lane;
      lds[d * 192 + x] = (_Float16)src[(size_t)d * HW + x];
    }
  }
  __syncthreads();
  _Float16* dst = galT2 + ((size_t)(g * 8 + kt)) * 12288;
  const int slot = t >> 5, row = t & 31;
#pragma unroll
  for (int rb = 0; rb < 6; ++rb) {
    half8 h;
#pragma unroll
    for (int j = 0; j < 8; ++j) h[j] = lds[(slot * 8 + j) * 192 + rb * 32 + row];
    *(half8*)(dst + rb * 2048 + slot * 256 + row * 8) = h;
  }
}

// ---- async 16B global -> LDS
__device__ __forceinline__ void g2l16(const void* g, void* l) {
  __builtin_amdgcn_global_load_lds(
      (const __attribute__((address_space(1))) void*)g,
      (__attribute__((address_space(3))) void*)l, 16, 0, 0);
}

// ---- main fused kernel: one WG (256 thr, 4 waves) per (g,p) pair ----
// 4 waves in 2(row wr) x 2(col wc) grid; each computes 96x96 via 3x3 frags of
// mfma_f32_32x32x16_f16.  B (gal) staged from pre-tiled galT2 by pure linear
// copy into conflict-free LDS layout [rb][slot][row32][16B] (BK=64, double-
// buffered); A (probe) loaded straight global->VGPR from fragment-ready
// probT2, register-double-buffered.  One plain __syncthreads per K-step.
__global__ __launch_bounds__(256, 2) void qaconv_main(
    const _Float16* __restrict__ galT2, const _Float16* __restrict__ probT2,
    const float* __restrict__ bn_w, const float* __restrict__ bn_b,
    const float* __restrict__ bn_m, const float* __restrict__ bn_v,
    const float* __restrict__ fc_w, const float* __restrict__ fc_b,
    const float* __restrict__ lbn_w, const float* __restrict__ lbn_b,
    const float* __restrict__ lbn_m, const float* __restrict__ lbn_v,
    float* __restrict__ out) {
  // union: K-loop bufB[2][24576] (49152 B) ; epilogue rowbuf[192][66] f32 (50688 B)
  __shared__ __align__(16) char shmem[50688];
  __shared__ float colp[2][HW];
  __shared__ float wsum[4];
  char* bufB = shmem;
  float(*rowbuf)[66] = (float(*)[66])shmem;

  const int bid = blockIdx.x;
  const int g = bid >> 6, p = bid & 63;

  const int t = threadIdx.x;
  const int lane = t & 63, wid = t >> 6;
  const int wr = wid & 1;   // probe-row half (y block of 96)
  const int wc = wid >> 1;  // gal-col half (x block of 96)
  const int l31 = lane & 31, hi = lane >> 5;
  const int arow0 = wr * 96 + l31;

  // A base: probT2 offset ((p*64 + s)*HW + r)*8, s = 2*idx + hi, idx = k-chunk 0..31
  const _Float16* aBase = probT2 + (((size_t)p * 64 + hi) * HW + arow0) * 8;

  // B staging: galT2 tile for (g,kt) is byte-identical to the LDS buffer;
  // thread t copies bytes [t*16 + r*4096] -> LDS same offsets (linear, coalesced).
  const _Float16* gB2 = galT2 + (size_t)g * 8 * 12288 + (size_t)t * 8;
  const int sdst = wid * 1024;  // wave-uniform LDS dest base (+ lane*16 by HW)

  floatx16 acc[3][3];
#pragma unroll
  for (int ii = 0; ii < 3; ++ii)
#pragma unroll
    for (int jj = 0; jj < 3; ++jj) acc[ii][jj] = (floatx16)0.f;

#define STAGE_B(kt_, buf_)                                          \
  {                                                                 \
    char* db_ = bufB + (buf_)*24576 + sdst;                         \
    const _Float16* sb_ = gB2 + (size_t)(kt_)*12288;                \
    _Pragma("unroll") for (int r_ = 0; r_ < 6; ++r_)                \
        g2l16(sb_ + (size_t)r_ * 2048, db_ + r_ * 4096);            \
  }

#define LOAD_AF(dst, idx_)                                          \
  {                                                                 \
    const _Float16* ap_ = aBase + (size_t)(idx_) * (2 * HW * 8);    \
    dst[0] = *(const half8*)(ap_);                                  \
    dst[1] = *(const half8*)(ap_ + 32 * 8);                         \
    dst[2] = *(const half8*)(ap_ + 64 * 8);                         \
  }

#define KC_BODY(kc_, AFU, AFL, nidx_)                                            \
  {                                                                              \
    LOAD_AF(AFL, nidx_);                                                         \
    half8 bf[3];                                                                 \
    const int boff_ = ((kc_)*2 + hi) * 512 + l31 * 16;                           \
    bf[0] = *(const half8*)(bcur + (wc * 3 + 0) * 4096 + boff_);                 \
    bf[1] = *(const half8*)(bcur + (wc * 3 + 1) * 4096 + boff_);                 \
    bf[2] = *(const half8*)(bcur + (wc * 3 + 2) * 4096 + boff_);                 \
    __builtin_amdgcn_s_setprio(1);                                               \
    _Pragma("unroll") for (int ii = 0; ii < 3; ++ii)                             \
        _Pragma("unroll") for (int jj = 0; jj < 3; ++jj)                         \
            acc[ii][jj] = __builtin_amdgcn_mfma_f32_32x32x16_f16(AFU[ii], bf[jj],\
                                                                 acc[ii][jj], 0, 0, 0); \
    __builtin_amdgcn_s_setprio(0);                                               \
  }

  half8 af0[3], af1[3];
  STAGE_B(0, 0);
  LOAD_AF(af0, 0);
  __syncthreads();  // prologue: full drain, B(0) staged by all waves

  for (int kt = 0; kt < 8; ++kt) {
    if (kt < 7) STAGE_B(kt + 1, (kt & 1) ^ 1);
    const char* bcur = bufB + (kt & 1) * 24576;
    const int i0 = kt * 4;
    const int n4 = (kt < 7) ? i0 + 4 : 31;  // clamp last prefetch (in-bounds dummy)
    KC_BODY(0, af0, af1, i0 + 1)
    KC_BODY(1, af1, af0, i0 + 2)
    KC_BODY(2, af0, af1, i0 + 3)
    KC_BODY(3, af1, af0, n4)
    __syncthreads();  // stage(kt+1) drained; all waves done reading bufB[kt&1]
  }

  // ---- epilogue: dual-axis max ----
  // C/D map: col X = wc*96 + fb*32 + l31, row Y = wr*96 + fa*32 + (e&3)+8*(e>>2)+4*hi
#pragma unroll
  for (int fb = 0; fb < 3; ++fb) {
    float v = -3.4e38f;
#pragma unroll
    for (int fa = 0; fa < 3; ++fa)
#pragma unroll
      for (int e = 0; e < 16; ++e) v = fmaxf(v, acc[fa][fb][e]);
    v = fmaxf(v, __shfl_xor(v, 32));
    if (lane < 32) colp[wr][wc * 96 + fb * 32 + lane] = v;
  }
  // rowmax partials -> rowbuf (overlays bufB; safe after the loop's final barrier)
#pragma unroll
  for (int fa = 0; fa < 3; ++fa)
#pragma unroll
    for (int e = 0; e < 16; ++e) {
      float rv = acc[fa][0][e];
      rv = fmaxf(rv, acc[fa][1][e]);
      rv = fmaxf(rv, acc[fa][2][e]);
      const int Y = wr * 96 + fa * 32 + (e & 3) + 8 * (e >> 2) + 4 * hi;
      rowbuf[Y][wc * 32 + l31] = rv;
    }
  __syncthreads();

  // ---- fused BN -> fc dot -> logit BN -> sigmoid ----
  float partial = 0.f;
  if (t < HW) {
    const float* rb = rowbuf[t];
    float rmax = -3.4e38f;
#pragma unroll
    for (int j = 0; j < 16; ++j) {
      const floatx4 v = *(const floatx4*)&rb[j * 4];
      rmax = fmaxf(rmax, fmaxf(fmaxf(v[0], v[1]), fmaxf(v[2], v[3])));
    }
    const float cmax = fmaxf(colp[0][t], colp[1][t]);
    const float scale = bn_w[0] / sqrtf(bn_v[0] + EPSV);
    const float bm = bn_m[0], bb = bn_b[0];
    partial = ((cmax - bm) * scale + bb) * fc_w[t] +
              ((rmax - bm) * scale + bb) * fc_w[HW + t];
  }
#pragma unroll
  for (int off = 1; off < 64; off <<= 1) partial += __shfl_xor(partial, off);
  if (lane == 0) wsum[wid] = partial;
  __syncthreads();
  if (t == 0) {
    const float sum = fc_b[0] + wsum[0] + wsum[1] + wsum[2] + wsum[3];
    const float logit = (sum - lbn_m[0]) * (lbn_w[0] / sqrtf(lbn_v[0] + EPSV)) + lbn_b[0];
    out[bid] = 1.f / (1.f + expf(-logit * 0.1f));
  }
#undef STAGE_B
#undef LOAD_AF
#undef KC_BODY
}

// ---------------- naive f32 fallback (only if ws too small) ----------------
__global__ __launch_bounds__(256) void qaconv_naive(
    const float* __restrict__ gal, const float* __restrict__ prob,
    const float* __restrict__ bn_w, const float* __restrict__ bn_b,
    const float* __restrict__ bn_m, const float* __restrict__ bn_v,
    const float* __restrict__ fc_w, const float* __restrict__ fc_b,
    const float* __restrict__ lbn_w, const float* __restrict__ lbn_b,
    const float* __restrict__ lbn_m, const float* __restrict__ lbn_v,
    float* __restrict__ out) {
  __shared__ float prow[ND];
  __shared__ float rowmaxs[HW];
  __shared__ float colmaxs[HW];
  __shared__ float red[4];
  const int bid = blockIdx.x;
  const int g = bid >> 6, p = bid & 63;
  const int t = threadIdx.x, lane = t & 63, wid = t >> 6;
  const float* gp = gal + (size_t)g * ND * HW;
  const float* pp = prob + (size_t)p * ND * HW;
  float colmax = -3.4e38f;
  for (int y = 0; y < HW; ++y) {
    for (int k = t; k < ND; k += 256) prow[k] = pp[(size_t)k * HW + y];
    __syncthreads();
    float sv = -3.4e38f;
    if (t < HW) {
      sv = 0.f;
      for (int k = 0; k < ND; ++k) sv = fmaf(prow[k], gp[(size_t)k * HW + t], sv);
      colmax = fmaxf(colmax, sv);
    }
    float m = sv;
#pragma unroll
    for (int off = 1; off < 64; off <<= 1) m = fmaxf(m, __shfl_xor(m, off));
    if (lane == 0) red[wid] = m;
    __syncthreads();
    if (t == 0) rowmaxs[y] = fmaxf(fmaxf(red[0], red[1]), fmaxf(red[2], red[3]));
    __syncthreads();
  }
  if (t < HW) colmaxs[t] = colmax;
  __syncthreads();
  float partial = 0.f;
  for (int j = t; j < 2 * HW; j += 256) {
    const float v = (j < HW) ? colmaxs[j] : rowmaxs[j - HW];
    const float sc = (v - bn_m[0]) * (bn_w[0] / sqrtf(bn_v[0] + EPSV)) + bn_b[0];
    partial += sc * fc_w[j];
  }
#pragma unroll
  for (int off = 1; off < 64; off <<= 1) partial += __shfl_xor(partial, off);
  if (lane == 0) red[wid] = partial;
  __syncthreads();
  if (t == 0) {
    const float sum = fc_b[0] + red[0] + red[1] + red[2] + red[3];
    const float logit = (sum - lbn_m[0]) * (lbn_w[0] / sqrtf(lbn_v[0] + EPSV)) + lbn_b[0];
    out[bid] = 1.f / (1.f + expf(-logit * 0.1f));
  }
}

extern "C" void kernel_launch(void* const* d_in, const int* in_sizes, int n_in,
                              void* d_out, int out_size, void* d_ws, size_t ws_size,
                              hipStream_t stream) {
  const float* gal = (const float*)d_in[0];
  const float* prob = (const float*)d_in[1];
  const float* bn_w = (const float*)d_in[2];
  const float* bn_b = (const float*)d_in[3];
  const float* bn_m = (const float*)d_in[4];
  const float* bn_v = (const float*)d_in[5];
  const float* fc_w = (const float*)d_in[6];
  const float* fc_b = (const float*)d_in[7];
  const float* lbn_w = (const float*)d_in[8];
  const float* lbn_b = (const float*)d_in[9];
  const float* lbn_m = (const float*)d_in[10];
  const float* lbn_v = (const float*)d_in[11];
  float* out = (float*)d_out;

  const size_t probT2_elems = (size_t)NP * 64 * HW * 8;  // 6.29M halves
  const size_t galT2_elems = (size_t)NG * 8 * 12288;     // 3.15M halves
  const size_t ws_needed = (probT2_elems + galT2_elems) * sizeof(_Float16);
  if (ws_size >= ws_needed) {
    _Float16* probT2 = (_Float16*)d_ws;
    _Float16* galT2 = probT2 + probT2_elems;
    prep_probe<<<dim3(NP, 64), dim3(192), 0, stream>>>(prob, probT2);
    prep_gal2<<<dim3(NG, 8), dim3(256), 0, stream>>>(gal, galT2);
    qaconv_main<<<dim3(NG * NP), dim3(256), 0, stream>>>(
        galT2, probT2, bn_w, bn_b, bn_m, bn_v, fc_w, fc_b, lbn_w, lbn_b, lbn_m, lbn_v, out);
  } else {
    qaconv_naive<<<dim3(NG * NP), dim3(256), 0, stream>>>(
        gal, prob, bn_w, bn_b, bn_m, bn_v, fc_w, fc_b, lbn_w, lbn_b, lbn_m, lbn_v, out);
  }
}